// Round 6
// baseline (19675.655 us; speedup 1.0000x reference)
//
#include <hip/hip_runtime.h>

namespace {

constexpr int KSTEPS = 1024;
constexpr int BTOT   = 512;
constexpr size_t OFF_R = (size_t)BTOT * KSTEPS * 5;                      // rates offset
constexpr size_t OFF_D = OFF_R + (size_t)BTOT * KSTEPS * 8;              // dhid offset

__device__ __forceinline__ float sigf(float x) {
    return 1.0f / (1.0f + __expf(-x));
}
__device__ __forceinline__ float tanhfast(float x) {
    float e2 = __expf(2.0f * x);
    return 1.0f - 2.0f / (e2 + 1.0f);   // inf-safe
}

// RHS of the 5-state chain (flux form, matches reference exactly)
#define CHAIN_RHS(d, yy)                                   \
    {                                                      \
        float f1 = kf1 * yy[0] - kr1 * yy[1];              \
        float f2 = kf2 * yy[1] - kr2 * yy[2];              \
        float f3 = kf3 * yy[2] - kr3 * yy[3];              \
        float f4 = kf4 * yy[3] - kr4 * yy[4];              \
        d[0] = -f1;                                        \
        d[1] = f1 - f2;                                    \
        d[2] = f2 - f3;                                    \
        d[3] = f3 - f4;                                    \
        d[4] = f4;                                         \
    }

// Register-budget model (validated rounds 1/3/4/5): backend budget =
// alignDown(256 / min_waves_per_eu, 4) — a 256-reg arch-VGPR pool, NOT 512.
// (3,3) -> 84 regs -> the 96 pinned weight floats spill to scratch (30 GB HBM).
// (1,3) -> 256-reg budget -> weights fit; runtime occupancy settles at
// 12 waves/CU (one 768-thread WG, VGPR ~150 allows 3 waves/EU).
__global__ __attribute__((amdgpu_flat_work_group_size(768, 768),
                          amdgpu_waves_per_eu(1, 3))) void rnn_v6(
    const float* __restrict__ y0,     const float* __restrict__ u_seq,
    const float* __restrict__ dt_seq, const float* __restrict__ W_lift,
    const float* __restrict__ b_lift, const float* __restrict__ W_ih,
    const float* __restrict__ W_hh,   const float* __restrict__ b_ih,
    const float* __restrict__ b_hh,   const float* __restrict__ W_head,
    const float* __restrict__ b_head, const float* __restrict__ u2y,
    float* __restrict__ out)
{
    const int t  = threadIdx.x;          // 0..767
    const int hf = (t >= 384) ? 1 : 0;   // column half (wave-uniform)
    const int o  = t - hf * 384;         // owned GRU output row 0..383
    const int wg = blockIdx.x;
    const int b0 = wg * 2;               // two batch rows per WG

    __shared__ alignas(16) float sWlift[64 * 9];
    __shared__ float sblift[64];
    __shared__ alignas(16) float sWheadP[13 * 132];   // padded stride 132
    __shared__ float sbhead[16];
    __shared__ float sU2Y[20];                        // (U=4, P=5) row-major
    __shared__ alignas(16) float sX[2][64];
    __shared__ alignas(16) float sH[2][128];
    __shared__ alignas(8) float sGiP[2][384][2];      // [half][out][row]
    __shared__ alignas(8) float sGhP[2][384][2];
    __shared__ float sY[2][8];
    __shared__ float sRates[2][8];
    __shared__ float sDhid[2][8];
    __shared__ alignas(16) float sU[2][2][4];         // [buf][row][4]
    __shared__ float sDt[2][2];

    // ---- per-thread half weight rows: 96 floats, register-resident ----
    float4 wih4[8];    // W_ih[o][hf*32 .. hf*32+31]
    float4 whh4[16];   // W_hh[o][hf*64 .. hf*64+63]
    {
        const float4* p = (const float4*)(W_ih + (size_t)o * 64 + hf * 32);
#pragma unroll
        for (int i = 0; i < 8; i++) wih4[i] = p[i];
        const float4* q = (const float4*)(W_hh + (size_t)o * 128 + hf * 64);
#pragma unroll
        for (int i = 0; i < 16; i++) whh4[i] = q[i];
    }
    const float bihv = hf ? 0.0f : b_ih[o];
    const float bhhv = hf ? 0.0f : b_hh[o];

    // ---- cooperative LDS init ----
    for (int i = t; i < 576; i += 768) sWlift[i] = W_lift[i];
    if (t < 64) sblift[t] = b_lift[t];
    for (int i = t; i < 13 * 128; i += 768) {
        int oo = i >> 7, c = i & 127;
        sWheadP[oo * 132 + c] = W_head[i];
    }
    if (t < 13) sbhead[t] = b_head[t];
    if (t < 20) sU2Y[t] = u2y[t];
    if (t < 256) sH[t >> 7][t & 127] = 0.0f;
    if (t < 10) { int r = t / 5, s = t % 5; sY[r][s] = y0[(b0 + r) * 5 + s] + 0.01f; }
    // gh(k=0) partials: h0 = 0 -> gh = b_hh (half 0 carries the bias)
    sGhP[hf][o][0] = bhhv;
    sGhP[hf][o][1] = bhhv;
    if (t < 8)  { int r = t >> 2, m = t & 3; sU[0][r][m] = u_seq[((size_t)(b0 + r) * KSTEPS + 0) * 4 + m]; }
    if (t >= 8 && t < 10) { int r = t - 8; sDt[0][r] = dt_seq[(size_t)(b0 + r) * KSTEPS + 0]; }
    __syncthreads();

    // ---- pin weights: asm redefines the values -> loads cannot be sunk/remat'd
    // into the loop; with the 256-reg budget they stay live in VGPRs.
#pragma unroll
    for (int i = 0; i < 8; i++)
        asm volatile("" : "+v"(wih4[i].x), "+v"(wih4[i].y), "+v"(wih4[i].z), "+v"(wih4[i].w));
#pragma unroll
    for (int i = 0; i < 16; i++)
        asm volatile("" : "+v"(whh4[i].x), "+v"(whh4[i].y), "+v"(whh4[i].z), "+v"(whh4[i].w));

    float4 upf = make_float4(0.f, 0.f, 0.f, 0.f);  // u prefetch (lanes 256,257)
    float  dpf = 0.f;                              // dt prefetch (lanes 258,259)

    for (int k = 0; k < KSTEPS; k++) {
        // ---------- phase A: prefetch issue + lift ----------
        if (t >= 256 && t < 260 && (k + 1) < KSTEPS) {
            if (t < 258) {
                int r = t - 256;
                upf = *(const float4*)&u_seq[((size_t)(b0 + r) * KSTEPS + (k + 1)) * 4];
            } else {
                int r = t - 258;
                dpf = dt_seq[(size_t)(b0 + r) * KSTEPS + (k + 1)];
            }
        }
        if (t < 128) {
            int r = t >> 6, l = t & 63;
            const float* wl = &sWlift[l * 9];
            float acc = sblift[l];
            acc = fmaf(wl[0], sU[k & 1][r][0], acc);
            acc = fmaf(wl[1], sU[k & 1][r][1], acc);
            acc = fmaf(wl[2], sU[k & 1][r][2], acc);
            acc = fmaf(wl[3], sU[k & 1][r][3], acc);
            acc = fmaf(wl[4], sY[r][0], acc);
            acc = fmaf(wl[5], sY[r][1], acc);
            acc = fmaf(wl[6], sY[r][2], acc);
            acc = fmaf(wl[7], sY[r][3], acc);
            acc = fmaf(wl[8], sY[r][4], acc);
            sX[r][l] = acc * sigf(acc);   // silu
        }
        __syncthreads();

        // ---------- phase B: gi half-partials (all 768 threads) ----------
        {
            float g0 = bihv, g1 = 0.0f;
            const float4* x0 = (const float4*)(&sX[0][hf * 32]);
            const float4* x1 = (const float4*)(&sX[1][hf * 32]);
#pragma unroll
            for (int i = 0; i < 8; i++) {
                float4 w = wih4[i];
                float4 a = x0[i];
                float4 c = x1[i];
                g0 = fmaf(w.x, a.x, g0); g0 = fmaf(w.y, a.y, g0);
                g0 = fmaf(w.z, a.z, g0); g0 = fmaf(w.w, a.w, g0);
                g1 = fmaf(w.x, c.x, g1); g1 = fmaf(w.y, c.y, g1);
                g1 = fmaf(w.z, c.z, g1); g1 = fmaf(w.w, c.w, g1);
            }
            *(float2*)&sGiP[hf][o][0] = make_float2(g0, g1);
        }
        __syncthreads();

        // ---------- phase C: GRU gates -> h_new ----------
        if (t < 256) {
            int r = t >> 7, q = t & 127;
            float ir  = sGiP[0][q][r]       + sGiP[1][q][r];
            float iz  = sGiP[0][q + 128][r] + sGiP[1][q + 128][r];
            float in_ = sGiP[0][q + 256][r] + sGiP[1][q + 256][r];
            float hr  = sGhP[0][q][r]       + sGhP[1][q][r];
            float hz  = sGhP[0][q + 128][r] + sGhP[1][q + 128][r];
            float hn  = sGhP[0][q + 256][r] + sGhP[1][q + 256][r];
            float rr = sigf(ir + hr);
            float z  = sigf(iz + hz);
            float n  = tanhfast(fmaf(rr, hn, in_));
            float h  = sH[r][q];
            sH[r][q] = fmaf(z, h - n, n);     // (1-z)*n + z*h
        }
        __syncthreads();

        // ---------- phase D: head, 8 lanes per output ----------
        if (t < 208) {
            int og = t >> 3, sub = t & 7;           // output group 0..25, sub-lane 0..7
            int r  = (og >= 13) ? 1 : 0;
            int oo = og - 13 * r;
            const float4* wv = (const float4*)(&sWheadP[oo * 132 + sub * 16]);
            const float4* hv = (const float4*)(&sH[r][sub * 16]);
            float4 w0 = wv[0], w1 = wv[1], w2 = wv[2], w3 = wv[3];
            float4 h0 = hv[0], h1 = hv[1], h2 = hv[2], h3 = hv[3];
            float a0 = w0.x * h0.x, a1 = w2.x * h2.x;
            a0 = fmaf(w0.y, h0.y, a0); a1 = fmaf(w2.y, h2.y, a1);
            a0 = fmaf(w0.z, h0.z, a0); a1 = fmaf(w2.z, h2.z, a1);
            a0 = fmaf(w0.w, h0.w, a0); a1 = fmaf(w2.w, h2.w, a1);
            a0 = fmaf(w1.x, h1.x, a0); a1 = fmaf(w3.x, h3.x, a1);
            a0 = fmaf(w1.y, h1.y, a0); a1 = fmaf(w3.y, h3.y, a1);
            a0 = fmaf(w1.z, h1.z, a0); a1 = fmaf(w3.z, h3.z, a1);
            a0 = fmaf(w1.w, h1.w, a0); a1 = fmaf(w3.w, h3.w, a1);
            float acc = a0 + a1;
            acc += __shfl_xor(acc, 1);
            acc += __shfl_xor(acc, 2);
            acc += __shfl_xor(acc, 4);
            if (sub == 0) {
                acc += sbhead[oo];
                if (oo < 8) {
                    float rate = fmaf(2.99f, sigf(acc), 0.01f);
                    sRates[r][oo] = rate;
                    out[OFF_R + ((size_t)(b0 + r) * KSTEPS + k) * 8 + oo] = rate;
                } else {
                    float dh = 3.0f * sigf(acc);
                    sDhid[r][oo - 8] = dh;
                    out[OFF_D + ((size_t)(b0 + r) * KSTEPS + k) * 5 + (oo - 8)] = dh;
                }
            }
        }
        __syncthreads();

        // ---------- phase E: gh(k+1) partials (all) || u commit || RK4 (lanes 0,1) ----------
        {
            float g0 = bhhv, g1 = 0.0f;
            const float4* h0 = (const float4*)(&sH[0][hf * 64]);
            const float4* h1 = (const float4*)(&sH[1][hf * 64]);
#pragma unroll
            for (int i = 0; i < 16; i++) {
                float4 w = whh4[i];
                float4 a = h0[i];
                float4 c = h1[i];
                g0 = fmaf(w.x, a.x, g0); g0 = fmaf(w.y, a.y, g0);
                g0 = fmaf(w.z, a.z, g0); g0 = fmaf(w.w, a.w, g0);
                g1 = fmaf(w.x, c.x, g1); g1 = fmaf(w.y, c.y, g1);
                g1 = fmaf(w.z, c.z, g1); g1 = fmaf(w.w, c.w, g1);
            }
            *(float2*)&sGhP[hf][o][0] = make_float2(g0, g1);
        }
        if (t >= 256 && t < 260 && (k + 1) < KSTEPS) {
            if (t < 258) {
                int r = t - 256;
                *(float4*)&sU[(k + 1) & 1][r][0] = upf;
            } else {
                sDt[(k + 1) & 1][t - 258] = dpf;
            }
        }
        if (t < 2) {
            const int r = t;
            float ya[5];
            float kf1 = sRates[r][0], kf2 = sRates[r][1], kf3 = sRates[r][2], kf4 = sRates[r][3];
            float kr1 = sRates[r][4], kr2 = sRates[r][5], kr3 = sRates[r][6], kr4 = sRates[r][7];
            float um0 = sU[k & 1][r][0], um1 = sU[k & 1][r][1];
            float um2 = sU[k & 1][r][2], um3 = sU[k & 1][r][3];
#pragma unroll
            for (int s = 0; s < 5; s++) {
                float jmp = um0 * sU2Y[s];
                jmp = fmaf(um1, sU2Y[5 + s], jmp);
                jmp = fmaf(um2, sU2Y[10 + s], jmp);
                jmp = fmaf(um3, sU2Y[15 + s], jmp);
                ya[s] = sY[r][s] + jmp + sDhid[r][s];
            }
            const float hs = sDt[k & 1][r] * 0.1f;     // dt / N_SUB
            const float h2 = 0.5f * hs;
            const float h6 = hs * (1.0f / 6.0f);
            for (int ss = 0; ss < 10; ss++) {
                float k1[5], k2[5], k3[5], k4[5], tp[5];
                CHAIN_RHS(k1, ya);
#pragma unroll
                for (int i = 0; i < 5; i++) tp[i] = fmaf(h2, k1[i], ya[i]);
                CHAIN_RHS(k2, tp);
#pragma unroll
                for (int i = 0; i < 5; i++) tp[i] = fmaf(h2, k2[i], ya[i]);
                CHAIN_RHS(k3, tp);
#pragma unroll
                for (int i = 0; i < 5; i++) tp[i] = fmaf(hs, k3[i], ya[i]);
                CHAIN_RHS(k4, tp);
#pragma unroll
                for (int i = 0; i < 5; i++) {
                    float sum = k1[i] + 2.0f * (k2[i] + k3[i]) + k4[i];
                    ya[i] = fmaxf(fmaf(h6, sum, ya[i]), 0.0f);
                }
            }
#pragma unroll
            for (int i = 0; i < 5; i++) {
                sY[r][i] = ya[i];
                out[((size_t)(b0 + r) * KSTEPS + k) * 5 + i] = ya[i];
            }
        }
        __syncthreads();
    }
}

}  // namespace

extern "C" void kernel_launch(void* const* d_in, const int* in_sizes, int n_in,
                              void* d_out, int out_size, void* d_ws, size_t ws_size,
                              hipStream_t stream) {
    const float* y0     = (const float*)d_in[0];
    const float* u_seq  = (const float*)d_in[1];
    const float* dt_seq = (const float*)d_in[2];
    const float* W_lift = (const float*)d_in[3];
    const float* b_lift = (const float*)d_in[4];
    const float* W_ih   = (const float*)d_in[5];
    const float* W_hh   = (const float*)d_in[6];
    const float* b_ih   = (const float*)d_in[7];
    const float* b_hh   = (const float*)d_in[8];
    const float* W_head = (const float*)d_in[9];
    const float* b_head = (const float*)d_in[10];
    const float* u2y    = (const float*)d_in[11];
    float* out = (float*)d_out;

    rnn_v6<<<256, 768, 0, stream>>>(y0, u_seq, dt_seq, W_lift, b_lift,
                                    W_ih, W_hh, b_ih, b_hh, W_head, b_head,
                                    u2y, out);
}

// Round 7
// 3584.771 us; speedup vs baseline: 5.4887x; 5.4887x over previous
//
#include <hip/hip_runtime.h>

namespace {

typedef _Float16 __attribute__((ext_vector_type(2))) h2v;   // one VGPR = 2 f16

constexpr int KSTEPS = 1024;
constexpr int BTOT   = 512;
constexpr size_t OFF_R = (size_t)BTOT * KSTEPS * 5;                      // rates offset
constexpr size_t OFF_D = OFF_R + (size_t)BTOT * KSTEPS * 8;              // dhid offset

__device__ __forceinline__ float sigf(float x) {
    return 1.0f / (1.0f + __expf(-x));
}
__device__ __forceinline__ float tanhfast(float x) {
    float e2 = __expf(2.0f * x);
    return 1.0f - 2.0f / (e2 + 1.0f);   // inf-safe
}
__device__ __forceinline__ float fdot2(h2v a, h2v b, float c) {
    return __builtin_amdgcn_fdot2(a, b, c, false);   // v_dot2_f32_f16
}

// RHS of the 5-state chain (flux form, matches reference exactly)
#define CHAIN_RHS(d, yy)                                   \
    {                                                      \
        float f1 = kf1 * yy[0] - kr1 * yy[1];              \
        float f2 = kf2 * yy[1] - kr2 * yy[2];              \
        float f3 = kf3 * yy[2] - kr3 * yy[3];              \
        float f4 = kf4 * yy[3] - kr4 * yy[4];              \
        d[0] = -f1;                                        \
        d[1] = f1 - f2;                                    \
        d[2] = f2 - f3;                                    \
        d[3] = f3 - f4;                                    \
        d[4] = f4;                                         \
    }

// Register-budget law (validated r1-r6): budget = 256 / ceil(waves_per_WG/4).
// 768-thread WG -> 84 VGPRs, immovable. So the weights must FIT 84:
// f16-packed pairs (48 VGPRs) + fdot2 fp32-accumulate.
__global__ __launch_bounds__(768, 3) void rnn_v7(
    const float* __restrict__ y0,     const float* __restrict__ u_seq,
    const float* __restrict__ dt_seq, const float* __restrict__ W_lift,
    const float* __restrict__ b_lift, const float* __restrict__ W_ih,
    const float* __restrict__ W_hh,   const float* __restrict__ b_ih,
    const float* __restrict__ b_hh,   const float* __restrict__ W_head,
    const float* __restrict__ b_head, const float* __restrict__ u2y,
    float* __restrict__ out)
{
    const int t  = threadIdx.x;          // 0..767
    const int hf = (t >= 384) ? 1 : 0;   // column half (wave-uniform)
    const int o  = t - hf * 384;         // owned GRU output row 0..383
    const int wg = blockIdx.x;
    const int b0 = wg * 2;               // two batch rows per WG

    __shared__ alignas(16) float sWlift[64 * 9];
    __shared__ float sblift[64];
    __shared__ alignas(16) float sWheadP[13 * 132];   // padded stride 132
    __shared__ float sbhead[16];
    __shared__ float sU2Y[20];                        // (U=4, P=5) row-major
    __shared__ alignas(16) _Float16 sX2[2][64];       // x as f16 (gi consumer only)
    __shared__ alignas(16) float sH[2][128];          // h fp32 (head consumer)
    __shared__ alignas(16) _Float16 sH2[2][128];      // h as f16 (gh consumer)
    __shared__ alignas(8) float sGiP[2][384][2];      // [half][out][row]
    __shared__ alignas(8) float sGhP[2][384][2];
    __shared__ float sY[2][8];
    __shared__ float sRates[2][8];
    __shared__ float sDhid[2][8];
    __shared__ alignas(16) float sU[2][2][4];         // [buf][row][4]
    __shared__ float sDt[2][2];

    // ---- per-thread half weight rows, f16-packed: 48 VGPRs total ----
    h2v wih2[16];   // W_ih[o][hf*32 .. +31]
    h2v whh2[32];   // W_hh[o][hf*64 .. +63]
    {
        const float* p = W_ih + (size_t)o * 64 + hf * 32;
#pragma unroll
        for (int i = 0; i < 16; i++)
            wih2[i] = h2v{(_Float16)p[2 * i], (_Float16)p[2 * i + 1]};
        const float* q = W_hh + (size_t)o * 128 + hf * 64;
#pragma unroll
        for (int i = 0; i < 32; i++)
            whh2[i] = h2v{(_Float16)q[2 * i], (_Float16)q[2 * i + 1]};
    }
    const float bihv = hf ? 0.0f : b_ih[o];
    const float bhhv = hf ? 0.0f : b_hh[o];

    // pin the packed weights: loads+cvt cannot be remat'd into the loop;
    // 48 regs fit the 84 budget so this cannot force a scratch spill.
#pragma unroll
    for (int i = 0; i < 16; i++) asm volatile("" : "+v"(wih2[i]));
#pragma unroll
    for (int i = 0; i < 32; i++) asm volatile("" : "+v"(whh2[i]));

    // ---- cooperative LDS init ----
    for (int i = t; i < 576; i += 768) sWlift[i] = W_lift[i];
    if (t < 64) sblift[t] = b_lift[t];
    for (int i = t; i < 13 * 128; i += 768) {
        int oo = i >> 7, c = i & 127;
        sWheadP[oo * 132 + c] = W_head[i];
    }
    if (t < 13) sbhead[t] = b_head[t];
    if (t < 20) sU2Y[t] = u2y[t];
    if (t < 256) {
        sH[t >> 7][t & 127] = 0.0f;
        sH2[t >> 7][t & 127] = (_Float16)0.0f;
    }
    if (t < 10) { int r = t / 5, s = t % 5; sY[r][s] = y0[(b0 + r) * 5 + s] + 0.01f; }
    // gh(k=0) partials: h0 = 0 -> gh = b_hh (half 0 carries the bias)
    sGhP[hf][o][0] = bhhv;
    sGhP[hf][o][1] = bhhv;
    if (t < 8)  { int r = t >> 2, m = t & 3; sU[0][r][m] = u_seq[((size_t)(b0 + r) * KSTEPS + 0) * 4 + m]; }
    if (t >= 8 && t < 10) { int r = t - 8; sDt[0][r] = dt_seq[(size_t)(b0 + r) * KSTEPS + 0]; }
    __syncthreads();

    float4 upf = make_float4(0.f, 0.f, 0.f, 0.f);  // u prefetch (lanes 256,257)
    float  dpf = 0.f;                              // dt prefetch (lanes 258,259)

    for (int k = 0; k < KSTEPS; k++) {
        // ---------- phase A: prefetch issue + lift ----------
        if (t >= 256 && t < 260 && (k + 1) < KSTEPS) {
            if (t < 258) {
                int r = t - 256;
                upf = *(const float4*)&u_seq[((size_t)(b0 + r) * KSTEPS + (k + 1)) * 4];
            } else {
                int r = t - 258;
                dpf = dt_seq[(size_t)(b0 + r) * KSTEPS + (k + 1)];
            }
        }
        if (t < 128) {
            int r = t >> 6, l = t & 63;
            const float* wl = &sWlift[l * 9];
            float acc = sblift[l];
            acc = fmaf(wl[0], sU[k & 1][r][0], acc);
            acc = fmaf(wl[1], sU[k & 1][r][1], acc);
            acc = fmaf(wl[2], sU[k & 1][r][2], acc);
            acc = fmaf(wl[3], sU[k & 1][r][3], acc);
            acc = fmaf(wl[4], sY[r][0], acc);
            acc = fmaf(wl[5], sY[r][1], acc);
            acc = fmaf(wl[6], sY[r][2], acc);
            acc = fmaf(wl[7], sY[r][3], acc);
            acc = fmaf(wl[8], sY[r][4], acc);
            sX2[r][l] = (_Float16)(acc * sigf(acc));   // silu, stored f16
        }
        __syncthreads();

        // ---------- phase B: gi half-partials via v_dot2_f32_f16 ----------
        {
            float g0 = bihv, g1 = 0.0f;
            const h2v* x0 = (const h2v*)&sX2[0][hf * 32];
            const h2v* x1 = (const h2v*)&sX2[1][hf * 32];
#pragma unroll
            for (int i = 0; i < 16; i++) {
                g0 = fdot2(wih2[i], x0[i], g0);
                g1 = fdot2(wih2[i], x1[i], g1);
            }
            *(float2*)&sGiP[hf][o][0] = make_float2(g0, g1);
        }
        __syncthreads();

        // ---------- phase C: GRU gates -> h_new ----------
        if (t < 256) {
            int r = t >> 7, q = t & 127;
            float ir  = sGiP[0][q][r]       + sGiP[1][q][r];
            float iz  = sGiP[0][q + 128][r] + sGiP[1][q + 128][r];
            float in_ = sGiP[0][q + 256][r] + sGiP[1][q + 256][r];
            float hr  = sGhP[0][q][r]       + sGhP[1][q][r];
            float hz  = sGhP[0][q + 128][r] + sGhP[1][q + 128][r];
            float hn  = sGhP[0][q + 256][r] + sGhP[1][q + 256][r];
            float rr = sigf(ir + hr);
            float z  = sigf(iz + hz);
            float n  = tanhfast(fmaf(rr, hn, in_));
            float h  = sH[r][q];
            float hnew = fmaf(z, h - n, n);     // (1-z)*n + z*h
            sH[r][q] = hnew;
            sH2[r][q] = (_Float16)hnew;
        }
        __syncthreads();

        // ---------- phase D: head, 8 lanes per output (fp32) ----------
        if (t < 208) {
            int og = t >> 3, sub = t & 7;           // output group 0..25, sub-lane 0..7
            int r  = (og >= 13) ? 1 : 0;
            int oo = og - 13 * r;
            const float4* wv = (const float4*)(&sWheadP[oo * 132 + sub * 16]);
            const float4* hv = (const float4*)(&sH[r][sub * 16]);
            float4 w0 = wv[0], w1 = wv[1], w2 = wv[2], w3 = wv[3];
            float4 h0 = hv[0], h1 = hv[1], h2 = hv[2], h3 = hv[3];
            float a0 = w0.x * h0.x, a1 = w2.x * h2.x;
            a0 = fmaf(w0.y, h0.y, a0); a1 = fmaf(w2.y, h2.y, a1);
            a0 = fmaf(w0.z, h0.z, a0); a1 = fmaf(w2.z, h2.z, a1);
            a0 = fmaf(w0.w, h0.w, a0); a1 = fmaf(w2.w, h2.w, a1);
            a0 = fmaf(w1.x, h1.x, a0); a1 = fmaf(w3.x, h3.x, a1);
            a0 = fmaf(w1.y, h1.y, a0); a1 = fmaf(w3.y, h3.y, a1);
            a0 = fmaf(w1.z, h1.z, a0); a1 = fmaf(w3.z, h3.z, a1);
            a0 = fmaf(w1.w, h1.w, a0); a1 = fmaf(w3.w, h3.w, a1);
            float acc = a0 + a1;
            acc += __shfl_xor(acc, 1);
            acc += __shfl_xor(acc, 2);
            acc += __shfl_xor(acc, 4);
            if (sub == 0) {
                acc += sbhead[oo];
                if (oo < 8) {
                    float rate = fmaf(2.99f, sigf(acc), 0.01f);
                    sRates[r][oo] = rate;
                    out[OFF_R + ((size_t)(b0 + r) * KSTEPS + k) * 8 + oo] = rate;
                } else {
                    float dh = 3.0f * sigf(acc);
                    sDhid[r][oo - 8] = dh;
                    out[OFF_D + ((size_t)(b0 + r) * KSTEPS + k) * 5 + (oo - 8)] = dh;
                }
            }
        }
        __syncthreads();

        // ---------- phase E: gh(k+1) partials (all) || u commit || RK4 (lanes 0,1) ----------
        {
            float g0 = bhhv, g1 = 0.0f;
            const h2v* h0p = (const h2v*)&sH2[0][hf * 64];
            const h2v* h1p = (const h2v*)&sH2[1][hf * 64];
#pragma unroll
            for (int i = 0; i < 32; i++) {
                g0 = fdot2(whh2[i], h0p[i], g0);
                g1 = fdot2(whh2[i], h1p[i], g1);
            }
            *(float2*)&sGhP[hf][o][0] = make_float2(g0, g1);
        }
        if (t >= 256 && t < 260 && (k + 1) < KSTEPS) {
            if (t < 258) {
                int r = t - 256;
                *(float4*)&sU[(k + 1) & 1][r][0] = upf;
            } else {
                sDt[(k + 1) & 1][t - 258] = dpf;
            }
        }
        if (t < 2) {
            const int r = t;
            float ya[5];
            float kf1 = sRates[r][0], kf2 = sRates[r][1], kf3 = sRates[r][2], kf4 = sRates[r][3];
            float kr1 = sRates[r][4], kr2 = sRates[r][5], kr3 = sRates[r][6], kr4 = sRates[r][7];
            float um0 = sU[k & 1][r][0], um1 = sU[k & 1][r][1];
            float um2 = sU[k & 1][r][2], um3 = sU[k & 1][r][3];
#pragma unroll
            for (int s = 0; s < 5; s++) {
                float jmp = um0 * sU2Y[s];
                jmp = fmaf(um1, sU2Y[5 + s], jmp);
                jmp = fmaf(um2, sU2Y[10 + s], jmp);
                jmp = fmaf(um3, sU2Y[15 + s], jmp);
                ya[s] = sY[r][s] + jmp + sDhid[r][s];
            }
            const float hs = sDt[k & 1][r] * 0.1f;     // dt / N_SUB
            const float h2 = 0.5f * hs;
            const float h6 = hs * (1.0f / 6.0f);
            for (int ss = 0; ss < 10; ss++) {
                float k1[5], k2[5], k3[5], k4[5], tp[5];
                CHAIN_RHS(k1, ya);
#pragma unroll
                for (int i = 0; i < 5; i++) tp[i] = fmaf(h2, k1[i], ya[i]);
                CHAIN_RHS(k2, tp);
#pragma unroll
                for (int i = 0; i < 5; i++) tp[i] = fmaf(h2, k2[i], ya[i]);
                CHAIN_RHS(k3, tp);
#pragma unroll
                for (int i = 0; i < 5; i++) tp[i] = fmaf(hs, k3[i], ya[i]);
                CHAIN_RHS(k4, tp);
#pragma unroll
                for (int i = 0; i < 5; i++) {
                    float sum = k1[i] + 2.0f * (k2[i] + k3[i]) + k4[i];
                    ya[i] = fmaxf(fmaf(h6, sum, ya[i]), 0.0f);
                }
            }
#pragma unroll
            for (int i = 0; i < 5; i++) {
                sY[r][i] = ya[i];
                out[((size_t)(b0 + r) * KSTEPS + k) * 5 + i] = ya[i];
            }
        }
        __syncthreads();
    }
}

}  // namespace

extern "C" void kernel_launch(void* const* d_in, const int* in_sizes, int n_in,
                              void* d_out, int out_size, void* d_ws, size_t ws_size,
                              hipStream_t stream) {
    const float* y0     = (const float*)d_in[0];
    const float* u_seq  = (const float*)d_in[1];
    const float* dt_seq = (const float*)d_in[2];
    const float* W_lift = (const float*)d_in[3];
    const float* b_lift = (const float*)d_in[4];
    const float* W_ih   = (const float*)d_in[5];
    const float* W_hh   = (const float*)d_in[6];
    const float* b_ih   = (const float*)d_in[7];
    const float* b_hh   = (const float*)d_in[8];
    const float* W_head = (const float*)d_in[9];
    const float* b_head = (const float*)d_in[10];
    const float* u2y    = (const float*)d_in[11];
    float* out = (float*)d_out;

    rnn_v7<<<256, 768, 0, stream>>>(y0, u_seq, dt_seq, W_lift, b_lift,
                                    W_ih, W_hh, b_ih, b_hh, W_head, b_head,
                                    u2y, out);
}